// Round 8
// baseline (790.643 us; speedup 1.0000x reference)
//
#include <hip/hip_runtime.h>
#include <hip/hip_bf16.h>
#include <stdint.h>

// Causal MHA, B=8 S=2048 E=768 N=12 H=64. fp32 in/out, bf16 MFMA compute.
// prep packs x, W_QKV, W_O into FRAGMENT-MAJOR layout -> qkv gemm and out gemm
// are barrier-free direct register GEMMs with an explicit 2-deep per-wave
// prefetch pipeline; R8: 4 waves/SIMD occupancy (launch_bounds 256,4) so
// sibling waves cover each wave's WAR/latency stalls.
// attn writes Z directly in fragment-major so out_gemm needs no repack.

#define B_ 8
#define S_ 2048
#define E_ 768
#define NHEADS 12
#define HD 64
#define BS (B_*S_)        // 16384
#define NHD (NHEADS*HD)   // 768

typedef short bf16x8 __attribute__((ext_vector_type(8)));   // 8 bf16 = 4 VGPR
typedef short bf16x4 __attribute__((ext_vector_type(4)));
typedef float f32x4  __attribute__((ext_vector_type(4)));   // MFMA C/D frag
typedef __hip_bfloat16 bf16;

__device__ __forceinline__ f32x4 mfma16(bf16x8 a, bf16x8 b, f32x4 c) {
    return __builtin_amdgcn_mfma_f32_16x16x32_bf16(a, b, c, 0, 0, 0);
}
__device__ __forceinline__ bf16x8 ld8(const bf16* p) {
    return *reinterpret_cast<const bf16x8*>(p);
}
__device__ __forceinline__ bf16x8 pack8(f32x4 a, f32x4 b) {
    union { bf16x8 v; __hip_bfloat162 h[4]; } u;
    u.h[0] = __float22bfloat162_rn(make_float2(a[0], a[1]));
    u.h[1] = __float22bfloat162_rn(make_float2(a[2], a[3]));
    u.h[2] = __float22bfloat162_rn(make_float2(b[0], b[1]));
    u.h[3] = __float22bfloat162_rn(make_float2(b[2], b[3]));
    return u.v;
}

// Fragment-major packed layout for an [R][768] row-major matrix:
// frag (rg = r/16, kc = k/32) occupies 512 elems at (rg*24 + kc)*512;
// element (rl=r%16, kq=(k%32)/8, e=k%8) sits at (kq*16 + rl)*8 + e.
// One ld8 at frag_base + lane*8 is exactly the 16x16x32 MFMA operand.

// ---------------- prep: pack x, W_QKV, W_O fragment-major --------------------
__global__ __launch_bounds__(256) void prep_kernel(
    const float* __restrict__ x,  const float* __restrict__ Wq,
    const float* __restrict__ Wk, const float* __restrict__ Wv,
    const float* __restrict__ Wo,
    bf16* __restrict__ xp,  bf16* __restrict__ WTp, bf16* __restrict__ WoTp)
{
    const int tid = blockIdx.x * 256 + threadIdx.x;
    const int nth = gridDim.x * 256;

    // x [16384][768] f32 -> packed bf16
    for (int c = tid; c < BS*E_/8; c += nth) {
        const int r  = c / 96;               // row
        const int k8 = (c - r*96) * 8;       // k start (multiple of 8)
        const float4 f0 = *reinterpret_cast<const float4*>(x + (size_t)r*E_ + k8);
        const float4 f1 = *reinterpret_cast<const float4*>(x + (size_t)r*E_ + k8 + 4);
        union { bf16x8 v; __hip_bfloat162 h[4]; } u;
        u.h[0] = __float22bfloat162_rn(make_float2(f0.x, f0.y));
        u.h[1] = __float22bfloat162_rn(make_float2(f0.z, f0.w));
        u.h[2] = __float22bfloat162_rn(make_float2(f1.x, f1.y));
        u.h[3] = __float22bfloat162_rn(make_float2(f1.z, f1.w));
        const size_t dst = (size_t)((r>>4)*24 + (k8>>5))*512
                         + (size_t)((((k8>>3)&3)<<4) + (r&15))*8;
        *reinterpret_cast<bf16x8*>(xp + dst) = u.v;
    }

    // W_{Q,K,V}[n][e][h] -> packed B rows r = mat*768 + (n*64+h), k = e
    for (int c2 = tid; c2 < NHD*96; c2 += nth) {
        const int r  = c2 / 96;              // (n,h) output-col index 0..767
        const int e8 = (c2 - r*96) * 8;      // k start
        const int n = r >> 6, h = r & 63;
        const float* sq = Wq + (size_t)(n*E_ + e8)*HD + h;
        const float* sk = Wk + (size_t)(n*E_ + e8)*HD + h;
        const float* sv = Wv + (size_t)(n*E_ + e8)*HD + h;
        union { bf16x8 v; bf16 el[8]; } uq, uk, uv;
        #pragma unroll
        for (int j = 0; j < 8; ++j) {
            uq.el[j] = __float2bfloat16(sq[(size_t)j*HD]);
            uk.el[j] = __float2bfloat16(sk[(size_t)j*HD]);
            uv.el[j] = __float2bfloat16(sv[(size_t)j*HD]);
        }
        const size_t sub = (size_t)(e8>>5)*512
                         + (size_t)((((e8>>3)&3)<<4) + (r&15))*8;
        const size_t rg  = (size_t)(r>>4);   // within-matrix row-group
        *reinterpret_cast<bf16x8*>(WTp + ((0*48 + rg)*24)*512 + sub) = uq.v;
        *reinterpret_cast<bf16x8*>(WTp + ((1*48 + rg)*24)*512 + sub) = uk.v;
        *reinterpret_cast<bf16x8*>(WTp + ((2*48 + rg)*24)*512 + sub) = uv.v;
    }

    // Wo flat[c][e] -> packed B^T rows e (0..767), k = c (0..767)
    for (int c3 = tid; c3 < E_*96; c3 += nth) {
        const int e  = c3 / 96;
        const int c8 = (c3 - e*96) * 8;
        union { bf16x8 v; bf16 el[8]; } u;
        #pragma unroll
        for (int j = 0; j < 8; ++j)
            u.el[j] = __float2bfloat16(Wo[(size_t)(c8 + j)*E_ + e]);
        const size_t dst = (size_t)((e>>4)*24 + (c8>>5))*512
                         + (size_t)((((c8>>3)&3)<<4) + (e&15))*8;
        *reinterpret_cast<bf16x8*>(WoTp + dst) = u.v;
    }
}

// ========== direct packed GEMM, explicit 2-deep prefetch pipeline ============
// Per body: issue next-K-tile loads into the dead operand set, sched_barrier(0)
// (pins loads above the MFMA cluster -> the auto-waitcnt for the live set
// becomes a counted vmcnt with a full K-tile of lead), then the MFMA cluster.
// No LDS, no barriers: waves free-run; 4 waves/SIMD cover WAR/latency stalls.

#define LOAD_A(dst, base, kt, NM)                                                 \
    _Pragma("unroll") for (int m = 0; m < NM; ++m)                                \
    _Pragma("unroll") for (int ks = 0; ks < 2; ++ks)                              \
        dst[m][ks] = ld8((base) + ((size_t)m*24 + (kt)*2 + ks)*512);

#define MFMA_BLK(af, bfv, NM, NN)                                                 \
    _Pragma("unroll") for (int ks = 0; ks < 2; ++ks)                              \
    _Pragma("unroll") for (int m = 0; m < NM; ++m)                                \
    _Pragma("unroll") for (int n = 0; n < NN; ++n)                                \
        acc[m][n] = mfma16(af[m][ks], bfv[n][ks], acc[m][n]);

#define DIRECT_PIPE_BODY(Abase, Bbase, NM, NN)                                    \
    f32x4 acc[NM][NN];                                                            \
    _Pragma("unroll") for (int mf = 0; mf < NM; ++mf)                             \
    _Pragma("unroll") for (int nf = 0; nf < NN; ++nf)                             \
        acc[mf][nf] = (f32x4){0.f, 0.f, 0.f, 0.f};                                \
    bf16x8 a0[NM][2], b0[NN][2], a1[NM][2], b1[NN][2];                            \
    LOAD_A(a0, Abase, 0, NM); LOAD_A(b0, Bbase, 0, NN);                           \
    _Pragma("unroll 1")                                                           \
    for (int kk = 0; kk < 6; ++kk) {                                              \
        const int ktA = 2*kk + 1;                                                 \
        const int ktB = (2*kk + 2 < 12) ? 2*kk + 2 : 11;                          \
        LOAD_A(a1, Abase, ktA, NM); LOAD_A(b1, Bbase, ktA, NN);                   \
        __builtin_amdgcn_sched_barrier(0);                                        \
        MFMA_BLK(a0, b0, NM, NN);                                                 \
        LOAD_A(a0, Abase, ktB, NM); LOAD_A(b0, Bbase, ktB, NN);                   \
        __builtin_amdgcn_sched_barrier(0);                                        \
        MFMA_BLK(a1, b1, NM, NN);                                                 \
    }

// ---------------- QKV projection: 128x128 blocks, wave tile 64x64 ------------
// WTp = packed [Wq;Wk;Wv] B-frags (144 row-groups); tn 0..17 spans it.
__global__ __launch_bounds__(256, 4) void qkv_gemm_p(
    const bf16* __restrict__ xp, const bf16* __restrict__ WTp,
    const float* __restrict__ bq, const float* __restrict__ bk, const float* __restrict__ bv,
    bf16* __restrict__ Qb, bf16* __restrict__ Kb, bf16* __restrict__ VTb)
{
    const int tm = blockIdx.x, tn = blockIdx.y;   // (128, 18)
    const int lane = threadIdx.x & 63;
    const int w    = threadIdx.x >> 6;            // 0..3
    const int wm = w >> 1, wn = w & 1;
    const int l16 = lane & 15, quad = lane >> 4;
    const bf16* Abase = xp  + ((size_t)(tm*8 + wm*4)*24)*512 + lane*8;
    const bf16* Bbase = WTp + ((size_t)(tn*8 + wn*4)*24)*512 + lane*8;

    DIRECT_PIPE_BODY(Abase, Bbase, 4, 4);

    const int mat = tn / 6;                  // 0=Q 1=K 2=V
    const int cloc0 = (tn - mat*6)*128 + wn*64;
    const float* bias = (mat==0) ? bq : (mat==1) ? bk : bv;
    const float scale = (mat==0) ? 0.125f * 1.44269504088896340736f : 1.0f;
    bf16* dstQK = (mat==0) ? Qb : Kb;
    #pragma unroll
    for (int nf = 0; nf < 4; ++nf) {
        const int col = cloc0 + nf*16 + l16;       // 0..767 within matrix
        const int hn = col >> 6, h = col & 63;
        const float bb = bias[col];
        #pragma unroll
        for (int mf = 0; mf < 4; ++mf) {
            const int row = tm*128 + wm*64 + mf*16 + quad*4;
            const int bi = row >> 11;              // / S_
            const int s  = row & (S_-1);
            if (mat < 2) {                         // Q,K -> [B][N][S][H]
                bf16* d = dstQK + ((size_t)(bi*NHEADS + hn)*S_ + s)*HD + h;
                #pragma unroll
                for (int r = 0; r < 4; ++r)
                    d[(size_t)r*HD] = __float2bfloat16((acc[mf][nf][r] + bb)*scale);
            } else {                               // V -> transposed [B][N][H][S]
                bf16* d = VTb + ((size_t)(bi*NHEADS + hn)*HD + h)*S_ + s;
                union { bf16x4 v; bf16 e[4]; } u;
                #pragma unroll
                for (int r = 0; r < 4; ++r) u.e[r] = __float2bfloat16(acc[mf][nf][r] + bb);
                *reinterpret_cast<bf16x4*>(d) = u.v;   // s%4==0 -> 8B aligned
            }
        }
    }
}

// ---------------- output projection: 128x96 blocks, wave tile 64x48 ----------
// A = Zp (fragment-major, written by attn), B = WoTp. Grid (128, 8) = exactly
// 1 dispatch round at 4 blocks/CU.
__global__ __launch_bounds__(256, 4) void out_gemm_p(
    const bf16* __restrict__ Zp, const bf16* __restrict__ WoTp,
    const float* __restrict__ bo, float* __restrict__ out)
{
    const int tm = blockIdx.x, tn = blockIdx.y;   // (128, 8)
    const int lane = threadIdx.x & 63;
    const int w    = threadIdx.x >> 6;
    const int wm = w >> 1, wn = w & 1;
    const int l16 = lane & 15, quad = lane >> 4;
    const bf16* Abase = Zp   + ((size_t)(tm*8 + wm*4)*24)*512 + lane*8;
    const bf16* Bbase = WoTp + ((size_t)(tn*6 + wn*3)*24)*512 + lane*8;

    DIRECT_PIPE_BODY(Abase, Bbase, 4, 3);

    #pragma unroll
    for (int nf = 0; nf < 3; ++nf) {
        const int col = tn*96 + wn*48 + nf*16 + l16;
        const float bb = bo[col];
        #pragma unroll
        for (int mf = 0; mf < 4; ++mf) {
            const int row = tm*128 + wm*64 + mf*16 + quad*4;
            float* d = out + (size_t)row*E_ + col;
            #pragma unroll
            for (int r = 0; r < 4; ++r)
                d[(size_t)r*E_] = acc[mf][nf][r] + bb;
        }
    }
}

// ---------------- flash attention (LDS-staged K/V, double-buffered) -----------
// Z is written directly in fragment-major (Zp) so out_gemm reads contiguous
// 1KB wave-loads.
__global__ __launch_bounds__(256, 3) void attn_kernel(
    const bf16* __restrict__ Qb, const bf16* __restrict__ Kb,
    const bf16* __restrict__ VTb, bf16* __restrict__ Zp)
{
    __shared__ __align__(16) bf16 sK[2][64*64];
    __shared__ __align__(16) bf16 sV[2][64*64];

    const int id = blockIdx.x;
    const int bx = id / 96;                  // 0..7
    const int g  = id - bx*96;
    const int hn = g % NHEADS, b = g / NHEADS;
    const int tid  = threadIdx.x;
    const int w    = tid >> 6;
    const int lane = tid & 63;
    const int l16 = lane & 15, quad = lane >> 4;
    const size_t bn = (size_t)b*NHEADS + hn;

    const bf16* Qbase = Qb  + bn*S_*HD;
    const bf16* Kbase = Kb  + bn*S_*HD;
    const bf16* Vbase = VTb + bn*HD*S_;

    const int mA = tid, mB = tid + 256;
    const int rA = mA >> 3, cgA = mA & 7;
    const int rB = mB >> 3, cgB = mB & 7;
    const int slA = (rA*8 + ((cgA + rA + (rA>>3)) & 7)) * 8;
    const int slB = (rB*8 + ((cgB + rB + (rB>>3)) & 7)) * 8;
    const size_t vofA = (size_t)rA*S_ + cgA*8;
    const size_t vofB = (size_t)rB*S_ + cgB*8;

    const int kperm = (l16 >> 2)*8 + (l16 & 3);
    int kidx[2][2][2];
    #pragma unroll
    for (int c=0;c<2;c++)
        #pragma unroll
        for (int bg=0;bg<2;bg++)
            #pragma unroll
            for (int hf=0;hf<2;hf++) {
                const int r = 32*c + 4*bg + kperm;
                const int q = hf*4 + quad;
                kidx[c][bg][hf] = (r*8 + ((q + r + (r>>3)) & 7)) * 8;
            }
    int vidx[4][2];
    #pragma unroll
    for (int ht=0;ht<4;ht++)
        #pragma unroll
        for (int c=0;c<2;c++) {
            const int rho = ht*16 + l16;
            const int q = c*4 + quad;
            vidx[ht][c] = (rho*8 + ((q + rho + (rho>>3)) & 7)) * 8;
        }

    #pragma unroll
    for (int half = 0; half < 2; ++half) {
        const int qblk = half ? (S_/128 - 1 - bx) : bx;
        const int ktb  = 2*qblk + 1;
        const int ktw  = 2*qblk + (w >> 1);
        const int qbase = qblk*128 + w*32;

        bf16x8 bqf[2][2];
        #pragma unroll
        for (int qi=0;qi<2;qi++)
            #pragma unroll
            for (int hf=0;hf<2;hf++)
                bqf[qi][hf] = ld8(Qbase + (size_t)(qbase + qi*16 + l16)*HD + hf*32 + quad*8);

        f32x4 acc[2][4];
        #pragma unroll
        for (int qi=0;qi<2;qi++)
            #pragma unroll
            for (int ht=0;ht<4;ht++) acc[qi][ht] = (f32x4){0.f,0.f,0.f,0.f};
        float lsum[2] = {0.f, 0.f};

        bf16x8 k0 = ld8(Kbase + (size_t)mA*8);
        bf16x8 k1 = ld8(Kbase + (size_t)mB*8);
        bf16x8 v0 = ld8(Vbase + vofA);
        bf16x8 v1 = ld8(Vbase + vofB);
        *reinterpret_cast<bf16x8*>(&sK[0][slA]) = k0;
        *reinterpret_cast<bf16x8*>(&sK[0][slB]) = k1;
        *reinterpret_cast<bf16x8*>(&sV[0][slA]) = v0;
        *reinterpret_cast<bf16x8*>(&sV[0][slB]) = v1;
        __syncthreads();

        for (int kt = 0; kt <= ktb; ++kt) {
            if (kt < ktb) {
                const size_t kt1 = (size_t)(kt+1)*64;
                k0 = ld8(Kbase + kt1*HD + (size_t)mA*8);
                k1 = ld8(Kbase + kt1*HD + (size_t)mB*8);
                v0 = ld8(Vbase + vofA + kt1);
                v1 = ld8(Vbase + vofB + kt1);
            }
            if (kt <= ktw) {
                const bf16* kb = sK[kt & 1];
                const bf16* vb = sV[kt & 1];
                #pragma unroll
                for (int c=0;c<2;c++) {
                    const bf16x8 akA0 = ld8(kb + kidx[c][0][0]);
                    const bf16x8 akA1 = ld8(kb + kidx[c][0][1]);
                    const bf16x8 akB0 = ld8(kb + kidx[c][1][0]);
                    const bf16x8 akB1 = ld8(kb + kidx[c][1][1]);
                    bf16x8 av[4];
                    #pragma unroll
                    for (int ht=0;ht<4;ht++) av[ht] = ld8(vb + vidx[ht][c]);

                    #pragma unroll
                    for (int qi=0;qi<2;qi++) {
                        f32x4 s0 = (f32x4){0.f,0.f,0.f,0.f};
                        s0 = mfma16(akA0, bqf[qi][0], s0);
                        s0 = mfma16(akA1, bqf[qi][1], s0);
                        f32x4 s1 = (f32x4){0.f,0.f,0.f,0.f};
                        s1 = mfma16(akB0, bqf[qi][0], s1);
                        s1 = mfma16(akB1, bqf[qi][1], s1);
                        if (kt == ktw) {
                            const int q  = qbase + qi*16 + l16;
                            const int kb0 = kt*64 + c*32 + quad*8;
                            #pragma unroll
                            for (int r=0;r<4;r++) {
                                s0[r] = (kb0 + r     > q) ? -1e30f : s0[r];
                                s1[r] = (kb0 + 4 + r > q) ? -1e30f : s1[r];
                            }
                        }
                        float ls = 0.f;
                        #pragma unroll
                        for (int r=0;r<4;r++) {
                            s0[r] = __builtin_amdgcn_exp2f(s0[r]);
                            s1[r] = __builtin_amdgcn_exp2f(s1[r]);
                            ls += s0[r] + s1[r];
                        }
                        lsum[qi] += ls;
                        const bf16x8 pf = pack8(s0, s1);
                        #pragma unroll
                        for (int ht=0;ht<4;ht++)
                            acc[qi][ht] = mfma16(av[ht], pf, acc[qi][ht]);
                    }
                }
            }
            if (kt < ktb) {
                const int nb = (kt+1) & 1;
                *reinterpret_cast<bf16x8*>(&sK[nb][slA]) = k0;
                *reinterpret_cast<bf16x8*>(&sK[nb][slB]) = k1;
                *reinterpret_cast<bf16x8*>(&sV[nb][slA]) = v0;
                *reinterpret_cast<bf16x8*>(&sV[nb][slB]) = v1;
            }
            __syncthreads();
        }

        #pragma unroll
        for (int qi=0;qi<2;qi++) {
            float rs = lsum[qi];
            rs += __shfl_xor(rs, 16, 64);
            rs += __shfl_xor(rs, 32, 64);
            const float inv_l = 1.0f / rs;
            // fragment-major Z write: row = b*S_+q (row&15 == l16),
            // rowg = row>>4; k = hn*64 + ht*16 + quad*4 (4 contiguous elems)
            const int rowg = b*128 + (qbase >> 4) + qi;
            #pragma unroll
            for (int ht=0;ht<4;ht++) {
                union { bf16x4 v; bf16 e[4]; } u;
                #pragma unroll
                for (int r=0;r<4;r++) u.e[r] = __float2bfloat16(acc[qi][ht][r] * inv_l);
                const int k = hn*64 + ht*16 + quad*4;
                bf16* d = Zp + ((size_t)rowg*24 + (k>>5))*512
                             + (size_t)((((k>>3)&3)<<4) + l16)*8 + (k&7);
                *reinterpret_cast<bf16x4*>(d) = u.v;   // 8B aligned
            }
        }
    }
}

extern "C" void kernel_launch(void* const* d_in, const int* in_sizes, int n_in,
                              void* d_out, int out_size, void* d_ws, size_t ws_size,
                              hipStream_t stream)
{
    const float* x  = (const float*)d_in[0];
    const float* Wq = (const float*)d_in[1];
    const float* Wk = (const float*)d_in[2];
    const float* Wv = (const float*)d_in[3];
    const float* Wo = (const float*)d_in[4];
    const float* bq = (const float*)d_in[5];
    const float* bk = (const float*)d_in[6];
    const float* bv = (const float*)d_in[7];
    const float* bo = (const float*)d_in[8];
    float* out = (float*)d_out;

    char* ws = (char*)d_ws;
    size_t off = 0;
    auto alloc = [&](size_t bytes){ char* p = ws + off; off += (bytes + 255) & ~(size_t)255; return p; };
    bf16* xp   = (bf16*)alloc((size_t)BS*E_*2);     // packed fragment-major
    bf16* WTp  = (bf16*)alloc((size_t)3*NHD*E_*2);  // packed [Wq;Wk;Wv] B-frags
    bf16* WoTp = (bf16*)alloc((size_t)E_*NHD*2);    // packed Wo^T B-frags
    bf16* Qb   = (bf16*)alloc((size_t)BS*NHD*2);    // [B][N][S][H], pre-scaled log2e/8
    bf16* Kb   = (bf16*)alloc((size_t)BS*NHD*2);    // [B][N][S][H]
    bf16* VTb  = (bf16*)alloc((size_t)BS*NHD*2);    // [B][N][H][S]
    bf16* Zp   = (bf16*)alloc((size_t)BS*NHD*2);    // fragment-major Z

    prep_kernel<<<4096, 256, 0, stream>>>(x, Wq, Wk, Wv, Wo, xp, WTp, WoTp);
    qkv_gemm_p<<<dim3(BS/128, 18), 256, 0, stream>>>(xp, WTp, bq, bk, bv, Qb, Kb, VTb);
    attn_kernel<<<768, 256, 0, stream>>>(Qb, Kb, VTb, Zp);
    out_gemm_p<<<dim3(BS/128, 8), 256, 0, stream>>>(Zp, WoTp, bo, out);
}

// Round 9
// 255.197 us; speedup vs baseline: 3.0982x; 3.0982x over previous
//
#include <hip/hip_runtime.h>
#include <hip/hip_bf16.h>
#include <stdint.h>

// Causal MHA, B=8 S=2048 E=768 N=12 H=64. fp32 in/out, bf16 MFMA compute.
// prep packs x, W_QKV, W_O into kc-major FRAGMENT blocks -> qkv/out gemms are
// barrier-free, LDS-free register GEMMs sized to fit 4 waves/SIMD (<=128 regs
// total): single operand set per half-K-tile, latency hidden by TLP (16
// free-running waves/CU), contiguous 1KB wave-loads, non-temporal epilogue
// stores. attn writes Z directly in the packed layout.

#define B_ 8
#define S_ 2048
#define E_ 768
#define NHEADS 12
#define HD 64
#define BS (B_*S_)        // 16384
#define NHD (NHEADS*HD)   // 768

typedef short bf16x8 __attribute__((ext_vector_type(8)));   // 8 bf16 = 4 VGPR
typedef short bf16x4 __attribute__((ext_vector_type(4)));
typedef float f32x4  __attribute__((ext_vector_type(4)));   // MFMA C/D frag
typedef __hip_bfloat16 bf16;

__device__ __forceinline__ f32x4 mfma16(bf16x8 a, bf16x8 b, f32x4 c) {
    return __builtin_amdgcn_mfma_f32_16x16x32_bf16(a, b, c, 0, 0, 0);
}
__device__ __forceinline__ bf16x8 ld8(const bf16* p) {
    return *reinterpret_cast<const bf16x8*>(p);
}
__device__ __forceinline__ void stnt_b16(bf16* p, bf16 v) {
    __builtin_nontemporal_store(*reinterpret_cast<short*>(&v),
                                reinterpret_cast<short*>(p));
}
__device__ __forceinline__ void stnt_b64(bf16* p, bf16x4 v) {
    __builtin_nontemporal_store(v, reinterpret_cast<bf16x4*>(p));
}
__device__ __forceinline__ void stnt_f32(float* p, float v) {
    __builtin_nontemporal_store(v, p);
}
__device__ __forceinline__ bf16x8 pack8(f32x4 a, f32x4 b) {
    union { bf16x8 v; __hip_bfloat162 h[4]; } u;
    u.h[0] = __float22bfloat162_rn(make_float2(a[0], a[1]));
    u.h[1] = __float22bfloat162_rn(make_float2(a[2], a[3]));
    u.h[2] = __float22bfloat162_rn(make_float2(b[0], b[1]));
    u.h[3] = __float22bfloat162_rn(make_float2(b[2], b[3]));
    return u.v;
}

// kc-major fragment-packed layout for an [R][K] matrix (K=768 -> 24 kc):
// frag (kc = k/32, rg = r/16) occupies 512 elems at (kc*NRG + rg)*512;
// element (rl=r%16, kq=(k%32)/8, e=k%8) sits at (kq*16 + rl)*8 + e.
// One ld8 at frag_base + lane*8 is the 16x16x32 MFMA operand; a half-K-tile's
// NRG-consecutive frags are CONTIGUOUS (imm-offset addressable).
// NRG: xp/Zp = 1024, WTp = 144, WoTp = 48.

// ---------------- prep: pack x, W_QKV, W_O (kc-major) ------------------------
__global__ __launch_bounds__(256) void prep_kernel(
    const float* __restrict__ x,  const float* __restrict__ Wq,
    const float* __restrict__ Wk, const float* __restrict__ Wv,
    const float* __restrict__ Wo,
    bf16* __restrict__ xp,  bf16* __restrict__ WTp, bf16* __restrict__ WoTp)
{
    const int tid = blockIdx.x * 256 + threadIdx.x;
    const int nth = gridDim.x * 256;

    // x [16384][768] f32 -> packed bf16
    for (int c = tid; c < BS*E_/8; c += nth) {
        const int r  = c / 96;               // row
        const int k8 = (c - r*96) * 8;       // k start (multiple of 8)
        const float4 f0 = *reinterpret_cast<const float4*>(x + (size_t)r*E_ + k8);
        const float4 f1 = *reinterpret_cast<const float4*>(x + (size_t)r*E_ + k8 + 4);
        union { bf16x8 v; __hip_bfloat162 h[4]; } u;
        u.h[0] = __float22bfloat162_rn(make_float2(f0.x, f0.y));
        u.h[1] = __float22bfloat162_rn(make_float2(f0.z, f0.w));
        u.h[2] = __float22bfloat162_rn(make_float2(f1.x, f1.y));
        u.h[3] = __float22bfloat162_rn(make_float2(f1.z, f1.w));
        const size_t dst = ((size_t)(k8>>5)*1024 + (r>>4))*512
                         + (size_t)((((k8>>3)&3)<<4) + (r&15))*8;
        *reinterpret_cast<bf16x8*>(xp + dst) = u.v;
    }

    // W_{Q,K,V}[n][e][h] -> packed B rows r_g = mat*768 + (n*64+h), k = e
    for (int c2 = tid; c2 < NHD*96; c2 += nth) {
        const int r  = c2 / 96;              // (n,h) output-col index 0..767
        const int e8 = (c2 - r*96) * 8;      // k start
        const int n = r >> 6, h = r & 63;
        const float* sq = Wq + (size_t)(n*E_ + e8)*HD + h;
        const float* sk = Wk + (size_t)(n*E_ + e8)*HD + h;
        const float* sv = Wv + (size_t)(n*E_ + e8)*HD + h;
        union { bf16x8 v; bf16 el[8]; } uq, uk, uv;
        #pragma unroll
        for (int j = 0; j < 8; ++j) {
            uq.el[j] = __float2bfloat16(sq[(size_t)j*HD]);
            uk.el[j] = __float2bfloat16(sk[(size_t)j*HD]);
            uv.el[j] = __float2bfloat16(sv[(size_t)j*HD]);
        }
        const size_t sub = (size_t)((((e8>>3)&3)<<4) + (r&15))*8;
        const size_t kcb = (size_t)(e8>>5)*144;
        const size_t rg  = (size_t)(r>>4);   // within-matrix row-group (0..47)
        *reinterpret_cast<bf16x8*>(WTp + (kcb + 0*48 + rg)*512 + sub) = uq.v;
        *reinterpret_cast<bf16x8*>(WTp + (kcb + 1*48 + rg)*512 + sub) = uk.v;
        *reinterpret_cast<bf16x8*>(WTp + (kcb + 2*48 + rg)*512 + sub) = uv.v;
    }

    // Wo flat[c][e] -> packed B rows e (0..767), k = c (0..767)
    for (int c3 = tid; c3 < E_*96; c3 += nth) {
        const int e  = c3 / 96;
        const int c8 = (c3 - e*96) * 8;
        union { bf16x8 v; bf16 el[8]; } u;
        #pragma unroll
        for (int j = 0; j < 8; ++j)
            u.el[j] = __float2bfloat16(Wo[(size_t)(c8 + j)*E_ + e]);
        const size_t dst = ((size_t)(c8>>5)*48 + (e>>4))*512
                         + (size_t)((((c8>>3)&3)<<4) + (e&15))*8;
        *reinterpret_cast<bf16x8*>(WoTp + dst) = u.v;
    }
}

// ========== direct packed GEMM, minimal-VGPR, 4 waves/SIMD ===================
// Wave tile 64x48: acc[4][3]=48 regs, one operand set a[4]+b[3]=28 regs,
// total ~95-112 incl addressing -> fits the 128-reg/4-wave budget (R8 lesson:
// the budget is total VGPR+AGPR, coarse steps 64/128/256). Per half-K-tile:
// 7 contiguous 1KB wave-loads -> wait -> 12 MFMA; 16 waves/CU free-run (no
// LDS, no barriers) so sibling waves cover each wave's load latency.

#define GEMM_MIN_BODY(pA, pB, strideB)                                            \
    f32x4 acc[4][3];                                                              \
    _Pragma("unroll") for (int mf = 0; mf < 4; ++mf)                              \
    _Pragma("unroll") for (int nf = 0; nf < 3; ++nf)                              \
        acc[mf][nf] = (f32x4){0.f, 0.f, 0.f, 0.f};                                \
    _Pragma("unroll 1")                                                           \
    for (int h = 0; h < 24; ++h) {                                                \
        bf16x8 a[4], b[3];                                                        \
        _Pragma("unroll") for (int m = 0; m < 4; ++m) a[m] = ld8(pA + m*512);     \
        _Pragma("unroll") for (int n = 0; n < 3; ++n) b[n] = ld8(pB + n*512);     \
        _Pragma("unroll") for (int m = 0; m < 4; ++m)                             \
        _Pragma("unroll") for (int n = 0; n < 3; ++n)                             \
            acc[m][n] = mfma16(a[m], b[n], acc[m][n]);                            \
        pA += 1024*512;                                                           \
        pB += (strideB)*512;                                                      \
    }

// ---------------- QKV projection: 128x96 blocks, wave tile 64x48 -------------
// WTp = packed [Wq;Wk;Wv] (NRG=144); tn 0..23 spans it. Grid 128x24 = 3072
// blocks = exactly 3 full rounds at 4 blocks/CU.
__global__ __launch_bounds__(256, 4) void qkv_gemm_p(
    const bf16* __restrict__ xp, const bf16* __restrict__ WTp,
    const float* __restrict__ bq, const float* __restrict__ bk, const float* __restrict__ bv,
    bf16* __restrict__ Qb, bf16* __restrict__ Kb, bf16* __restrict__ VTb)
{
    const int tm = blockIdx.x, tn = blockIdx.y;   // (128, 24)
    const int lane = threadIdx.x & 63;
    const int w    = threadIdx.x >> 6;            // 0..3
    const int wm = w >> 1, wn = w & 1;
    const int l16 = lane & 15, quad = lane >> 4;
    const bf16* pA = xp  + (size_t)(tm*8 + wm*4)*512 + lane*8;
    const bf16* pB = WTp + (size_t)(tn*6 + wn*3)*512 + lane*8;

    GEMM_MIN_BODY(pA, pB, 144);

    const int mat = tn >> 3;                 // 0=Q 1=K 2=V
    const int cloc0 = (tn & 7)*96 + wn*48;
    const float* bias = (mat==0) ? bq : (mat==1) ? bk : bv;
    const float scale = (mat==0) ? 0.125f * 1.44269504088896340736f : 1.0f;
    bf16* dstQK = (mat==0) ? Qb : Kb;
    #pragma unroll
    for (int nf = 0; nf < 3; ++nf) {
        const int col = cloc0 + nf*16 + l16;       // 0..767 within matrix
        const int hn = col >> 6, h = col & 63;
        const float bb = bias[col];
        #pragma unroll
        for (int mf = 0; mf < 4; ++mf) {
            const int row = tm*128 + wm*64 + mf*16 + quad*4;
            const int bi = row >> 11;              // / S_
            const int s  = row & (S_-1);
            if (mat < 2) {                         // Q,K -> [B][N][S][H]
                bf16* d = dstQK + ((size_t)(bi*NHEADS + hn)*S_ + s)*HD + h;
                #pragma unroll
                for (int r = 0; r < 4; ++r)
                    stnt_b16(d + (size_t)r*HD,
                             __float2bfloat16((acc[mf][nf][r] + bb)*scale));
            } else {                               // V -> transposed [B][N][H][S]
                bf16* d = VTb + ((size_t)(bi*NHEADS + hn)*HD + h)*S_ + s;
                union { bf16x4 v; bf16 e[4]; } u;
                #pragma unroll
                for (int r = 0; r < 4; ++r) u.e[r] = __float2bfloat16(acc[mf][nf][r] + bb);
                stnt_b64(d, u.v);                  // s%4==0 -> 8B aligned
            }
        }
    }
}

// ---------------- output projection: 128x96 blocks, wave tile 64x48 ----------
// A = Zp (packed, written by attn, NRG=1024), B = WoTp (NRG=48).
// Grid (128, 8) = 1024 blocks = exactly 1 round at 4 blocks/CU.
__global__ __launch_bounds__(256, 4) void out_gemm_p(
    const bf16* __restrict__ Zp, const bf16* __restrict__ WoTp,
    const float* __restrict__ bo, float* __restrict__ out)
{
    const int tm = blockIdx.x, tn = blockIdx.y;   // (128, 8)
    const int lane = threadIdx.x & 63;
    const int w    = threadIdx.x >> 6;
    const int wm = w >> 1, wn = w & 1;
    const int l16 = lane & 15, quad = lane >> 4;
    const bf16* pA = Zp   + (size_t)(tm*8 + wm*4)*512 + lane*8;
    const bf16* pB = WoTp + (size_t)(tn*6 + wn*3)*512 + lane*8;

    GEMM_MIN_BODY(pA, pB, 48);

    #pragma unroll
    for (int nf = 0; nf < 3; ++nf) {
        const int col = tn*96 + wn*48 + nf*16 + l16;
        const float bb = bo[col];
        #pragma unroll
        for (int mf = 0; mf < 4; ++mf) {
            const int row = tm*128 + wm*64 + mf*16 + quad*4;
            float* d = out + (size_t)row*E_ + col;
            #pragma unroll
            for (int r = 0; r < 4; ++r)
                stnt_f32(d + (size_t)r*E_, acc[mf][nf][r] + bb);
        }
    }
}

// ---------------- flash attention (LDS-staged K/V, double-buffered) -----------
// Unchanged except the Zp write index (kc-major packed layout).
__global__ __launch_bounds__(256, 3) void attn_kernel(
    const bf16* __restrict__ Qb, const bf16* __restrict__ Kb,
    const bf16* __restrict__ VTb, bf16* __restrict__ Zp)
{
    __shared__ __align__(16) bf16 sK[2][64*64];
    __shared__ __align__(16) bf16 sV[2][64*64];

    const int id = blockIdx.x;
    const int bx = id / 96;                  // 0..7
    const int g  = id - bx*96;
    const int hn = g % NHEADS, b = g / NHEADS;
    const int tid  = threadIdx.x;
    const int w    = tid >> 6;
    const int lane = tid & 63;
    const int l16 = lane & 15, quad = lane >> 4;
    const size_t bn = (size_t)b*NHEADS + hn;

    const bf16* Qbase = Qb  + bn*S_*HD;
    const bf16* Kbase = Kb  + bn*S_*HD;
    const bf16* Vbase = VTb + bn*HD*S_;

    const int mA = tid, mB = tid + 256;
    const int rA = mA >> 3, cgA = mA & 7;
    const int rB = mB >> 3, cgB = mB & 7;
    const int slA = (rA*8 + ((cgA + rA + (rA>>3)) & 7)) * 8;
    const int slB = (rB*8 + ((cgB + rB + (rB>>3)) & 7)) * 8;
    const size_t vofA = (size_t)rA*S_ + cgA*8;
    const size_t vofB = (size_t)rB*S_ + cgB*8;

    const int kperm = (l16 >> 2)*8 + (l16 & 3);
    int kidx[2][2][2];
    #pragma unroll
    for (int c=0;c<2;c++)
        #pragma unroll
        for (int bg=0;bg<2;bg++)
            #pragma unroll
            for (int hf=0;hf<2;hf++) {
                const int r = 32*c + 4*bg + kperm;
                const int q = hf*4 + quad;
                kidx[c][bg][hf] = (r*8 + ((q + r + (r>>3)) & 7)) * 8;
            }
    int vidx[4][2];
    #pragma unroll
    for (int ht=0;ht<4;ht++)
        #pragma unroll
        for (int c=0;c<2;c++) {
            const int rho = ht*16 + l16;
            const int q = c*4 + quad;
            vidx[ht][c] = (rho*8 + ((q + rho + (rho>>3)) & 7)) * 8;
        }

    #pragma unroll
    for (int half = 0; half < 2; ++half) {
        const int qblk = half ? (S_/128 - 1 - bx) : bx;
        const int ktb  = 2*qblk + 1;
        const int ktw  = 2*qblk + (w >> 1);
        const int qbase = qblk*128 + w*32;

        bf16x8 bqf[2][2];
        #pragma unroll
        for (int qi=0;qi<2;qi++)
            #pragma unroll
            for (int hf=0;hf<2;hf++)
                bqf[qi][hf] = ld8(Qbase + (size_t)(qbase + qi*16 + l16)*HD + hf*32 + quad*8);

        f32x4 acc[2][4];
        #pragma unroll
        for (int qi=0;qi<2;qi++)
            #pragma unroll
            for (int ht=0;ht<4;ht++) acc[qi][ht] = (f32x4){0.f,0.f,0.f,0.f};
        float lsum[2] = {0.f, 0.f};

        bf16x8 k0 = ld8(Kbase + (size_t)mA*8);
        bf16x8 k1 = ld8(Kbase + (size_t)mB*8);
        bf16x8 v0 = ld8(Vbase + vofA);
        bf16x8 v1 = ld8(Vbase + vofB);
        *reinterpret_cast<bf16x8*>(&sK[0][slA]) = k0;
        *reinterpret_cast<bf16x8*>(&sK[0][slB]) = k1;
        *reinterpret_cast<bf16x8*>(&sV[0][slA]) = v0;
        *reinterpret_cast<bf16x8*>(&sV[0][slB]) = v1;
        __syncthreads();

        for (int kt = 0; kt <= ktb; ++kt) {
            if (kt < ktb) {
                const size_t kt1 = (size_t)(kt+1)*64;
                k0 = ld8(Kbase + kt1*HD + (size_t)mA*8);
                k1 = ld8(Kbase + kt1*HD + (size_t)mB*8);
                v0 = ld8(Vbase + vofA + kt1);
                v1 = ld8(Vbase + vofB + kt1);
            }
            if (kt <= ktw) {
                const bf16* kb = sK[kt & 1];
                const bf16* vb = sV[kt & 1];
                #pragma unroll
                for (int c=0;c<2;c++) {
                    const bf16x8 akA0 = ld8(kb + kidx[c][0][0]);
                    const bf16x8 akA1 = ld8(kb + kidx[c][0][1]);
                    const bf16x8 akB0 = ld8(kb + kidx[c][1][0]);
                    const bf16x8 akB1 = ld8(kb + kidx[c][1][1]);
                    bf16x8 av[4];
                    #pragma unroll
                    for (int ht=0;ht<4;ht++) av[ht] = ld8(vb + vidx[ht][c]);

                    #pragma unroll
                    for (int qi=0;qi<2;qi++) {
                        f32x4 s0 = (f32x4){0.f,0.f,0.f,0.f};
                        s0 = mfma16(akA0, bqf[qi][0], s0);
                        s0 = mfma16(akA1, bqf[qi][1], s0);
                        f32x4 s1 = (f32x4){0.f,0.f,0.f,0.f};
                        s1 = mfma16(akB0, bqf[qi][0], s1);
                        s1 = mfma16(akB1, bqf[qi][1], s1);
                        if (kt == ktw) {
                            const int q  = qbase + qi*16 + l16;
                            const int kb0 = kt*64 + c*32 + quad*8;
                            #pragma unroll
                            for (int r=0;r<4;r++) {
                                s0[r] = (kb0 + r     > q) ? -1e30f : s0[r];
                                s1[r] = (kb0 + 4 + r > q) ? -1e30f : s1[r];
                            }
                        }
                        float ls = 0.f;
                        #pragma unroll
                        for (int r=0;r<4;r++) {
                            s0[r] = __builtin_amdgcn_exp2f(s0[r]);
                            s1[r] = __builtin_amdgcn_exp2f(s1[r]);
                            ls += s0[r] + s1[r];
                        }
                        lsum[qi] += ls;
                        const bf16x8 pf = pack8(s0, s1);
                        #pragma unroll
                        for (int ht=0;ht<4;ht++)
                            acc[qi][ht] = mfma16(av[ht], pf, acc[qi][ht]);
                    }
                }
            }
            if (kt < ktb) {
                const int nb = (kt+1) & 1;
                *reinterpret_cast<bf16x8*>(&sK[nb][slA]) = k0;
                *reinterpret_cast<bf16x8*>(&sK[nb][slB]) = k1;
                *reinterpret_cast<bf16x8*>(&sV[nb][slA]) = v0;
                *reinterpret_cast<bf16x8*>(&sV[nb][slB]) = v1;
            }
            __syncthreads();
        }

        #pragma unroll
        for (int qi=0;qi<2;qi++) {
            float rs = lsum[qi];
            rs += __shfl_xor(rs, 16, 64);
            rs += __shfl_xor(rs, 32, 64);
            const float inv_l = 1.0f / rs;
            // kc-major packed Z write: global row rowg = (b*2048+q)>>4,
            // k = hn*64 + ht*16 + quad*4 (4 contiguous elems, 8B aligned)
            const int rowg = b*128 + (qbase >> 4) + qi;
            #pragma unroll
            for (int ht=0;ht<4;ht++) {
                union { bf16x4 v; bf16 e[4]; } u;
                #pragma unroll
                for (int r=0;r<4;r++) u.e[r] = __float2bfloat16(acc[qi][ht][r] * inv_l);
                const int k = hn*64 + ht*16 + quad*4;
                bf16* d = Zp + ((size_t)(k>>5)*1024 + rowg)*512
                             + (size_t)((((k>>3)&3)<<4) + l16)*8 + (k&7);
                *reinterpret_cast<bf16x4*>(d) = u.v;
            }
        }
    }
}

extern "C" void kernel_launch(void* const* d_in, const int* in_sizes, int n_in,
                              void* d_out, int out_size, void* d_ws, size_t ws_size,
                              hipStream_t stream)
{
    const float* x  = (const float*)d_in[0];
    const float* Wq = (const float*)d_in[1];
    const float* Wk = (const float*)d_in[2];
    const float* Wv = (const float*)d_in[3];
    const float* Wo = (const float*)d_in[4];
    const float* bq = (const float*)d_in[5];
    const float* bk = (const float*)d_in[6];
    const float* bv = (const float*)d_in[7];
    const float* bo = (const float*)d_in[8];
    float* out = (float*)d_out;

    char* ws = (char*)d_ws;
    size_t off = 0;
    auto alloc = [&](size_t bytes){ char* p = ws + off; off += (bytes + 255) & ~(size_t)255; return p; };
    bf16* xp   = (bf16*)alloc((size_t)BS*E_*2);     // packed kc-major (NRG=1024)
    bf16* WTp  = (bf16*)alloc((size_t)3*NHD*E_*2);  // packed [Wq;Wk;Wv] (NRG=144)
    bf16* WoTp = (bf16*)alloc((size_t)E_*NHD*2);    // packed Wo^T (NRG=48)
    bf16* Qb   = (bf16*)alloc((size_t)BS*NHD*2);    // [B][N][S][H], pre-scaled log2e/8
    bf16* Kb   = (bf16*)alloc((size_t)BS*NHD*2);    // [B][N][S][H]
    bf16* VTb  = (bf16*)alloc((size_t)BS*NHD*2);    // [B][N][H][S]
    bf16* Zp   = (bf16*)alloc((size_t)BS*NHD*2);    // packed Z (NRG=1024)

    prep_kernel<<<4096, 256, 0, stream>>>(x, Wq, Wk, Wv, Wo, xp, WTp, WoTp);
    qkv_gemm_p<<<dim3(BS/128, 24), 256, 0, stream>>>(xp, WTp, bq, bk, bv, Qb, Kb, VTb);
    attn_kernel<<<768, 256, 0, stream>>>(Qb, Kb, VTb, Zp);
    out_gemm_p<<<dim3(BS/128, 8), 256, 0, stream>>>(Zp, WoTp, bo, out);
}

// Round 10
// 232.755 us; speedup vs baseline: 3.3969x; 1.0964x over previous
//
#include <hip/hip_runtime.h>
#include <hip/hip_bf16.h>
#include <stdint.h>

// Causal MHA, B=8 S=2048 E=768 N=12 H=64. fp32 in/out, bf16 MFMA compute.
// prep packs x, W_QKV, W_O into FRAGMENT-MAJOR layout -> qkv/out gemms are
// barrier-free direct register GEMMs (R7 config: 2-set prefetch pipeline,
// launch_bounds(256,2) -- at the L1-BW roofline ~28% MfmaUtil).
// attn: R10 = 3-buffer LDS + 2-tiles-ahead K/V register prefetch + setprio
// around MFMA clusters. attn writes Z in fragment-major for out_gemm.

#define B_ 8
#define S_ 2048
#define E_ 768
#define NHEADS 12
#define HD 64
#define BS (B_*S_)        // 16384
#define NHD (NHEADS*HD)   // 768

typedef short bf16x8 __attribute__((ext_vector_type(8)));   // 8 bf16 = 4 VGPR
typedef short bf16x4 __attribute__((ext_vector_type(4)));
typedef float f32x4  __attribute__((ext_vector_type(4)));   // MFMA C/D frag
typedef __hip_bfloat16 bf16;

__device__ __forceinline__ f32x4 mfma16(bf16x8 a, bf16x8 b, f32x4 c) {
    return __builtin_amdgcn_mfma_f32_16x16x32_bf16(a, b, c, 0, 0, 0);
}
__device__ __forceinline__ bf16x8 ld8(const bf16* p) {
    return *reinterpret_cast<const bf16x8*>(p);
}
__device__ __forceinline__ bf16x8 pack8(f32x4 a, f32x4 b) {
    union { bf16x8 v; __hip_bfloat162 h[4]; } u;
    u.h[0] = __float22bfloat162_rn(make_float2(a[0], a[1]));
    u.h[1] = __float22bfloat162_rn(make_float2(a[2], a[3]));
    u.h[2] = __float22bfloat162_rn(make_float2(b[0], b[1]));
    u.h[3] = __float22bfloat162_rn(make_float2(b[2], b[3]));
    return u.v;
}

// Fragment-major packed layout for an [R][768] row-major matrix:
// frag (rg = r/16, kc = k/32) occupies 512 elems at (rg*24 + kc)*512;
// element (rl=r%16, kq=(k%32)/8, e=k%8) sits at (kq*16 + rl)*8 + e.
// One ld8 at frag_base + lane*8 is exactly the 16x16x32 MFMA operand.

// ---------------- prep: pack x, W_QKV, W_O fragment-major --------------------
__global__ __launch_bounds__(256) void prep_kernel(
    const float* __restrict__ x,  const float* __restrict__ Wq,
    const float* __restrict__ Wk, const float* __restrict__ Wv,
    const float* __restrict__ Wo,
    bf16* __restrict__ xp,  bf16* __restrict__ WTp, bf16* __restrict__ WoTp)
{
    const int tid = blockIdx.x * 256 + threadIdx.x;
    const int nth = gridDim.x * 256;

    // x [16384][768] f32 -> packed bf16
    for (int c = tid; c < BS*E_/8; c += nth) {
        const int r  = c / 96;               // row
        const int k8 = (c - r*96) * 8;       // k start (multiple of 8)
        const float4 f0 = *reinterpret_cast<const float4*>(x + (size_t)r*E_ + k8);
        const float4 f1 = *reinterpret_cast<const float4*>(x + (size_t)r*E_ + k8 + 4);
        union { bf16x8 v; __hip_bfloat162 h[4]; } u;
        u.h[0] = __float22bfloat162_rn(make_float2(f0.x, f0.y));
        u.h[1] = __float22bfloat162_rn(make_float2(f0.z, f0.w));
        u.h[2] = __float22bfloat162_rn(make_float2(f1.x, f1.y));
        u.h[3] = __float22bfloat162_rn(make_float2(f1.z, f1.w));
        const size_t dst = (size_t)((r>>4)*24 + (k8>>5))*512
                         + (size_t)((((k8>>3)&3)<<4) + (r&15))*8;
        *reinterpret_cast<bf16x8*>(xp + dst) = u.v;
    }

    // W_{Q,K,V}[n][e][h] -> packed B rows r = mat*768 + (n*64+h), k = e
    for (int c2 = tid; c2 < NHD*96; c2 += nth) {
        const int r  = c2 / 96;              // (n,h) output-col index 0..767
        const int e8 = (c2 - r*96) * 8;      // k start
        const int n = r >> 6, h = r & 63;
        const float* sq = Wq + (size_t)(n*E_ + e8)*HD + h;
        const float* sk = Wk + (size_t)(n*E_ + e8)*HD + h;
        const float* sv = Wv + (size_t)(n*E_ + e8)*HD + h;
        union { bf16x8 v; bf16 el[8]; } uq, uk, uv;
        #pragma unroll
        for (int j = 0; j < 8; ++j) {
            uq.el[j] = __float2bfloat16(sq[(size_t)j*HD]);
            uk.el[j] = __float2bfloat16(sk[(size_t)j*HD]);
            uv.el[j] = __float2bfloat16(sv[(size_t)j*HD]);
        }
        const size_t sub = (size_t)(e8>>5)*512
                         + (size_t)((((e8>>3)&3)<<4) + (r&15))*8;
        const size_t rg  = (size_t)(r>>4);   // within-matrix row-group
        *reinterpret_cast<bf16x8*>(WTp + ((0*48 + rg)*24)*512 + sub) = uq.v;
        *reinterpret_cast<bf16x8*>(WTp + ((1*48 + rg)*24)*512 + sub) = uk.v;
        *reinterpret_cast<bf16x8*>(WTp + ((2*48 + rg)*24)*512 + sub) = uv.v;
    }

    // Wo flat[c][e] -> packed B^T rows e (0..767), k = c (0..767)
    for (int c3 = tid; c3 < E_*96; c3 += nth) {
        const int e  = c3 / 96;
        const int c8 = (c3 - e*96) * 8;
        union { bf16x8 v; bf16 el[8]; } u;
        #pragma unroll
        for (int j = 0; j < 8; ++j)
            u.el[j] = __float2bfloat16(Wo[(size_t)(c8 + j)*E_ + e]);
        const size_t dst = (size_t)((e>>4)*24 + (c8>>5))*512
                         + (size_t)((((c8>>3)&3)<<4) + (e&15))*8;
        *reinterpret_cast<bf16x8*>(WoTp + dst) = u.v;
    }
}

// ========== direct packed GEMM, explicit 2-deep prefetch pipeline ============
// R7 config (best measured): launch_bounds(256,2), VGPR~100, MfmaUtil ~28% =
// the L1-BW roofline for a 64x64 wave tile (500 B/MFMA vs ~128 B/cyc L1).

#define LOAD_A(dst, base, kt, NM)                                                 \
    _Pragma("unroll") for (int m = 0; m < NM; ++m)                                \
    _Pragma("unroll") for (int ks = 0; ks < 2; ++ks)                              \
        dst[m][ks] = ld8((base) + ((size_t)m*24 + (kt)*2 + ks)*512);

#define MFMA_BLK(af, bfv, NM, NN)                                                 \
    _Pragma("unroll") for (int ks = 0; ks < 2; ++ks)                              \
    _Pragma("unroll") for (int m = 0; m < NM; ++m)                                \
    _Pragma("unroll") for (int n = 0; n < NN; ++n)                                \
        acc[m][n] = mfma16(af[m][ks], bfv[n][ks], acc[m][n]);

#define DIRECT_PIPE_BODY(Abase, Bbase, NM, NN)                                    \
    f32x4 acc[NM][NN];                                                            \
    _Pragma("unroll") for (int mf = 0; mf < NM; ++mf)                             \
    _Pragma("unroll") for (int nf = 0; nf < NN; ++nf)                             \
        acc[mf][nf] = (f32x4){0.f, 0.f, 0.f, 0.f};                                \
    bf16x8 a0[NM][2], b0[NN][2], a1[NM][2], b1[NN][2];                            \
    LOAD_A(a0, Abase, 0, NM); LOAD_A(b0, Bbase, 0, NN);                           \
    _Pragma("unroll 1")                                                           \
    for (int kk = 0; kk < 6; ++kk) {                                              \
        const int ktA = 2*kk + 1;                                                 \
        const int ktB = (2*kk + 2 < 12) ? 2*kk + 2 : 11;                          \
        LOAD_A(a1, Abase, ktA, NM); LOAD_A(b1, Bbase, ktA, NN);                   \
        __builtin_amdgcn_sched_barrier(0);                                        \
        MFMA_BLK(a0, b0, NM, NN);                                                 \
        LOAD_A(a0, Abase, ktB, NM); LOAD_A(b0, Bbase, ktB, NN);                   \
        __builtin_amdgcn_sched_barrier(0);                                        \
        MFMA_BLK(a1, b1, NM, NN);                                                 \
    }

// ---------------- QKV projection: 128x128 blocks, wave tile 64x64 ------------
__global__ __launch_bounds__(256, 2) void qkv_gemm_p(
    const bf16* __restrict__ xp, const bf16* __restrict__ WTp,
    const float* __restrict__ bq, const float* __restrict__ bk, const float* __restrict__ bv,
    bf16* __restrict__ Qb, bf16* __restrict__ Kb, bf16* __restrict__ VTb)
{
    const int tm = blockIdx.x, tn = blockIdx.y;   // (128, 18)
    const int lane = threadIdx.x & 63;
    const int w    = threadIdx.x >> 6;            // 0..3
    const int wm = w >> 1, wn = w & 1;
    const int l16 = lane & 15, quad = lane >> 4;
    const bf16* Abase = xp  + ((size_t)(tm*8 + wm*4)*24)*512 + lane*8;
    const bf16* Bbase = WTp + ((size_t)(tn*8 + wn*4)*24)*512 + lane*8;

    DIRECT_PIPE_BODY(Abase, Bbase, 4, 4);

    const int mat = tn / 6;                  // 0=Q 1=K 2=V
    const int cloc0 = (tn - mat*6)*128 + wn*64;
    const float* bias = (mat==0) ? bq : (mat==1) ? bk : bv;
    const float scale = (mat==0) ? 0.125f * 1.44269504088896340736f : 1.0f;
    bf16* dstQK = (mat==0) ? Qb : Kb;
    #pragma unroll
    for (int nf = 0; nf < 4; ++nf) {
        const int col = cloc0 + nf*16 + l16;       // 0..767 within matrix
        const int hn = col >> 6, h = col & 63;
        const float bb = bias[col];
        #pragma unroll
        for (int mf = 0; mf < 4; ++mf) {
            const int row = tm*128 + wm*64 + mf*16 + quad*4;
            const int bi = row >> 11;              // / S_
            const int s  = row & (S_-1);
            if (mat < 2) {                         // Q,K -> [B][N][S][H]
                bf16* d = dstQK + ((size_t)(bi*NHEADS + hn)*S_ + s)*HD + h;
                #pragma unroll
                for (int r = 0; r < 4; ++r)
                    d[(size_t)r*HD] = __float2bfloat16((acc[mf][nf][r] + bb)*scale);
            } else {                               // V -> transposed [B][N][H][S]
                bf16* d = VTb + ((size_t)(bi*NHEADS + hn)*HD + h)*S_ + s;
                union { bf16x4 v; bf16 e[4]; } u;
                #pragma unroll
                for (int r = 0; r < 4; ++r) u.e[r] = __float2bfloat16(acc[mf][nf][r] + bb);
                *reinterpret_cast<bf16x4*>(d) = u.v;   // s%4==0 -> 8B aligned
            }
        }
    }
}

// ---------------- output projection: 128x96 blocks, wave tile 64x48 ----------
__global__ __launch_bounds__(256, 2) void out_gemm_p(
    const bf16* __restrict__ Zp, const bf16* __restrict__ WoTp,
    const float* __restrict__ bo, float* __restrict__ out)
{
    const int tm = blockIdx.x, tn = blockIdx.y;   // (128, 8)
    const int lane = threadIdx.x & 63;
    const int w    = threadIdx.x >> 6;
    const int wm = w >> 1, wn = w & 1;
    const int l16 = lane & 15, quad = lane >> 4;
    const bf16* Abase = Zp   + ((size_t)(tm*8 + wm*4)*24)*512 + lane*8;
    const bf16* Bbase = WoTp + ((size_t)(tn*6 + wn*3)*24)*512 + lane*8;

    DIRECT_PIPE_BODY(Abase, Bbase, 4, 3);

    #pragma unroll
    for (int nf = 0; nf < 3; ++nf) {
        const int col = tn*96 + wn*48 + nf*16 + l16;
        const float bb = bo[col];
        #pragma unroll
        for (int mf = 0; mf < 4; ++mf) {
            const int row = tm*128 + wm*64 + mf*16 + quad*4;
            float* d = out + (size_t)row*E_ + col;
            #pragma unroll
            for (int r = 0; r < 4; ++r)
                d[(size_t)r*E_] = acc[mf][nf][r] + bb;
        }
    }
}

// ---------------- flash attention: 3-buffer LDS, 2-tiles-ahead prefetch ------
// Per kt: write regs(tile kt+1) -> buf[(kt+1)%3] (loads issued a full kt ago
// -> latency covered), issue loads(tile kt+2), compute from buf[kt%3] with
// setprio(1) around MFMA clusters, ONE barrier. Buffer ledger: read kt%3 /
// write (kt+1)%3 / in-flight (kt+2)%3 are distinct; written buffer's last
// reads were >=1 barrier ago. LDS 48KB -> 3 blocks/CU unchanged.
__global__ __launch_bounds__(256, 3) void attn_kernel(
    const bf16* __restrict__ Qb, const bf16* __restrict__ Kb,
    const bf16* __restrict__ VTb, bf16* __restrict__ Zp)
{
    __shared__ __align__(16) bf16 sK[3*4096];
    __shared__ __align__(16) bf16 sV[3*4096];

    const int id = blockIdx.x;
    const int bx = id / 96;                  // 0..7
    const int g  = id - bx*96;
    const int hn = g % NHEADS, b = g / NHEADS;
    const int tid  = threadIdx.x;
    const int w    = tid >> 6;
    const int lane = tid & 63;
    const int l16 = lane & 15, quad = lane >> 4;
    const size_t bn = (size_t)b*NHEADS + hn;

    const bf16* Qbase = Qb  + bn*S_*HD;
    const bf16* Kbase = Kb  + bn*S_*HD;
    const bf16* Vbase = VTb + bn*HD*S_;

    const int mA = tid, mB = tid + 256;
    const int rA = mA >> 3, cgA = mA & 7;
    const int rB = mB >> 3, cgB = mB & 7;
    const int slA = (rA*8 + ((cgA + rA + (rA>>3)) & 7)) * 8;
    const int slB = (rB*8 + ((cgB + rB + (rB>>3)) & 7)) * 8;
    const size_t vofA = (size_t)rA*S_ + cgA*8;
    const size_t vofB = (size_t)rB*S_ + cgB*8;

    const int kperm = (l16 >> 2)*8 + (l16 & 3);
    int kidx[2][2][2];
    #pragma unroll
    for (int c=0;c<2;c++)
        #pragma unroll
        for (int bg=0;bg<2;bg++)
            #pragma unroll
            for (int hf=0;hf<2;hf++) {
                const int r = 32*c + 4*bg + kperm;
                const int q = hf*4 + quad;
                kidx[c][bg][hf] = (r*8 + ((q + r + (r>>3)) & 7)) * 8;
            }
    int vidx[4][2];
    #pragma unroll
    for (int ht=0;ht<4;ht++)
        #pragma unroll
        for (int c=0;c<2;c++) {
            const int rho = ht*16 + l16;
            const int q = c*4 + quad;
            vidx[ht][c] = (rho*8 + ((q + rho + (rho>>3)) & 7)) * 8;
        }

    #pragma unroll
    for (int half = 0; half < 2; ++half) {
        const int qblk = half ? (S_/128 - 1 - bx) : bx;
        const int ktb  = 2*qblk + 1;             // >= 1 always
        const int ktw  = 2*qblk + (w >> 1);
        const int qbase = qblk*128 + w*32;

        bf16x8 bqf[2][2];
        #pragma unroll
        for (int qi=0;qi<2;qi++)
            #pragma unroll
            for (int hf=0;hf<2;hf++)
                bqf[qi][hf] = ld8(Qbase + (size_t)(qbase + qi*16 + l16)*HD + hf*32 + quad*8);

        f32x4 acc[2][4];
        #pragma unroll
        for (int qi=0;qi<2;qi++)
            #pragma unroll
            for (int ht=0;ht<4;ht++) acc[qi][ht] = (f32x4){0.f,0.f,0.f,0.f};
        float lsum[2] = {0.f, 0.f};

        // prologue: tile 0 -> buf0; tile 1 -> regs
        bf16x8 k0 = ld8(Kbase + (size_t)mA*8);
        bf16x8 k1 = ld8(Kbase + (size_t)mB*8);
        bf16x8 v0 = ld8(Vbase + vofA);
        bf16x8 v1 = ld8(Vbase + vofB);
        *reinterpret_cast<bf16x8*>(&sK[slA]) = k0;
        *reinterpret_cast<bf16x8*>(&sK[slB]) = k1;
        *reinterpret_cast<bf16x8*>(&sV[slA]) = v0;
        *reinterpret_cast<bf16x8*>(&sV[slB]) = v1;
        k0 = ld8(Kbase + 4096 + (size_t)mA*8);
        k1 = ld8(Kbase + 4096 + (size_t)mB*8);
        v0 = ld8(Vbase + vofA + 64);
        v1 = ld8(Vbase + vofB + 64);
        __syncthreads();

        int rd = 0, wr = 1, l3 = 2;
        for (int kt = 0; kt <= ktb; ++kt) {
            if (kt + 1 <= ktb) {                 // write tile kt+1 to buf wr
                bf16* kw = sK + wr*4096;
                bf16* vw = sV + wr*4096;
                *reinterpret_cast<bf16x8*>(&kw[slA]) = k0;
                *reinterpret_cast<bf16x8*>(&kw[slB]) = k1;
                *reinterpret_cast<bf16x8*>(&vw[slA]) = v0;
                *reinterpret_cast<bf16x8*>(&vw[slB]) = v1;
            }
            if (kt + 2 <= ktb) {                 // issue loads for tile kt+2
                const size_t o = (size_t)(kt + 2) * 64;
                k0 = ld8(Kbase + o*HD + (size_t)mA*8);
                k1 = ld8(Kbase + o*HD + (size_t)mB*8);
                v0 = ld8(Vbase + vofA + o);
                v1 = ld8(Vbase + vofB + o);
            }
            if (kt <= ktw) {
                const bf16* kb = sK + rd*4096;
                const bf16* vb = sV + rd*4096;
                #pragma unroll
                for (int c=0;c<2;c++) {
                    const bf16x8 akA0 = ld8(kb + kidx[c][0][0]);
                    const bf16x8 akA1 = ld8(kb + kidx[c][0][1]);
                    const bf16x8 akB0 = ld8(kb + kidx[c][1][0]);
                    const bf16x8 akB1 = ld8(kb + kidx[c][1][1]);
                    bf16x8 av[4];
                    #pragma unroll
                    for (int ht=0;ht<4;ht++) av[ht] = ld8(vb + vidx[ht][c]);

                    #pragma unroll
                    for (int qi=0;qi<2;qi++) {
                        __builtin_amdgcn_s_setprio(1);
                        f32x4 s0 = (f32x4){0.f,0.f,0.f,0.f};
                        s0 = mfma16(akA0, bqf[qi][0], s0);
                        s0 = mfma16(akA1, bqf[qi][1], s0);
                        f32x4 s1 = (f32x4){0.f,0.f,0.f,0.f};
                        s1 = mfma16(akB0, bqf[qi][0], s1);
                        s1 = mfma16(akB1, bqf[qi][1], s1);
                        __builtin_amdgcn_s_setprio(0);
                        if (kt == ktw) {
                            const int q  = qbase + qi*16 + l16;
                            const int kb0 = kt*64 + c*32 + quad*8;
                            #pragma unroll
                            for (int r=0;r<4;r++) {
                                s0[r] = (kb0 + r     > q) ? -1e30f : s0[r];
                                s1[r] = (kb0 + 4 + r > q) ? -1e30f : s1[r];
                            }
                        }
                        float ls = 0.f;
                        #pragma unroll
                        for (int r=0;r<4;r++) {
                            s0[r] = __builtin_amdgcn_exp2f(s0[r]);
                            s1[r] = __builtin_amdgcn_exp2f(s1[r]);
                            ls += s0[r] + s1[r];
                        }
                        lsum[qi] += ls;
                        const bf16x8 pf = pack8(s0, s1);
                        __builtin_amdgcn_s_setprio(1);
                        #pragma unroll
                        for (int ht=0;ht<4;ht++)
                            acc[qi][ht] = mfma16(av[ht], pf, acc[qi][ht]);
                        __builtin_amdgcn_s_setprio(0);
                    }
                }
            }
            __syncthreads();
            const int t = rd; rd = wr; wr = l3; l3 = t;
        }

        #pragma unroll
        for (int qi=0;qi<2;qi++) {
            float rs = lsum[qi];
            rs += __shfl_xor(rs, 16, 64);
            rs += __shfl_xor(rs, 32, 64);
            const float inv_l = 1.0f / rs;
            // fragment-major Z write: rowg = (b*2048+q)>>4,
            // k = hn*64 + ht*16 + quad*4 (4 contiguous elems, 8B aligned)
            const int rowg = b*128 + (qbase >> 4) + qi;
            #pragma unroll
            for (int ht=0;ht<4;ht++) {
                union { bf16x4 v; bf16 e[4]; } u;
                #pragma unroll
                for (int r=0;r<4;r++) u.e[r] = __float2bfloat16(acc[qi][ht][r] * inv_l);
                const int k = hn*64 + ht*16 + quad*4;
                bf16* d = Zp + ((size_t)rowg*24 + (k>>5))*512
                             + (size_t)((((k>>3)&3)<<4) + l16)*8 + (k&7);
                *reinterpret_cast<bf16x4*>(d) = u.v;
            }
        }
    }
}

extern "C" void kernel_launch(void* const* d_in, const int* in_sizes, int n_in,
                              void* d_out, int out_size, void* d_ws, size_t ws_size,
                              hipStream_t stream)
{
    const float* x  = (const float*)d_in[0];
    const float* Wq = (const float*)d_in[1];
    const float* Wk = (const float*)d_in[2];
    const float* Wv = (const float*)d_in[3];
    const float* Wo = (const float*)d_in[4];
    const float* bq = (const float*)d_in[5];
    const float* bk = (const float*)d_in[6];
    const float* bv = (const float*)d_in[7];
    const float* bo = (const float*)d_in[8];
    float* out = (float*)d_out;

    char* ws = (char*)d_ws;
    size_t off = 0;
    auto alloc = [&](size_t bytes){ char* p = ws + off; off += (bytes + 255) & ~(size_t)255; return p; };
    bf16* xp   = (bf16*)alloc((size_t)BS*E_*2);     // packed fragment-major
    bf16* WTp  = (bf16*)alloc((size_t)3*NHD*E_*2);  // packed [Wq;Wk;Wv] B-frags
    bf16* WoTp = (bf16*)alloc((size_t)E_*NHD*2);    // packed Wo^T B-frags
    bf16* Qb   = (bf16*)alloc((size_t)BS*NHD*2);    // [B][N][S][H], pre-scaled log2e/8
    bf16* Kb   = (bf16*)alloc((size_t)BS*NHD*2);    // [B][N][S][H]
    bf16* VTb  = (bf16*)alloc((size_t)BS*NHD*2);    // [B][N][H][S]
    bf16* Zp   = (bf16*)alloc((size_t)BS*NHD*2);    // fragment-major Z

    prep_kernel<<<4096, 256, 0, stream>>>(x, Wq, Wk, Wv, Wo, xp, WTp, WoTp);
    qkv_gemm_p<<<dim3(BS/128, 18), 256, 0, stream>>>(xp, WTp, bq, bk, bv, Qb, Kb, VTb);
    attn_kernel<<<768, 256, 0, stream>>>(Qb, Kb, VTb, Zp);
    out_gemm_p<<<dim3(BS/128, 8), 256, 0, stream>>>(Zp, WoTp, bo, out);
}